// Round 1
// baseline (73.013 us; speedup 1.0000x reference)
//
#include <hip/hip_runtime.h>
#include <hip/hip_bf16.h>

// PairRE scoring: out[b,n] = -|| t_hat[n]*rt[b] - h_hat[b]*rh[b] ||_2
// B=512, N=2048, E=256, NREL=1000.
//
// Decomposition: x = sum_e (T*rt)^2 - 2 sum_e T*rt*Hh + sum_e Hh^2
//   with T = t/||t||, Hh = (h/||h||)*rh.
// => x(b,n) = dot( [T^2 | T]_n , [rt^2 | -2*rt*Hh]_b ) + c_b,  c_b = ||Hh_b||^2
// One bf16 GEMM, M=2048 (n), N=512 (b), K=512, fp32 accumulate, epilogue -sqrt.

#define B_DIM 512
#define N_DIM 2048
#define E_DIM 256
#define K_DIM 512

typedef __attribute__((ext_vector_type(8))) __bf16 bf16x8;
typedef __attribute__((ext_vector_type(4))) float f32x4;

__device__ inline ushort f2bf(float x) {
    __hip_bfloat16 h = __float2bfloat16(x);   // round-to-nearest-even
    union { __hip_bfloat16 b; ushort u; } cv; cv.b = h; return cv.u;
}

// sum across 256 threads, result broadcast to all. buf: float[4] LDS.
__device__ inline float block_reduce_sum_256(float v, float* buf) {
#pragma unroll
    for (int o = 32; o > 0; o >>= 1) v += __shfl_down(v, o, 64);
    const int lane = threadIdx.x & 63, wid = threadIdx.x >> 6;
    __syncthreads();                 // protect buf against back-to-back use
    if (lane == 0) buf[wid] = v;
    __syncthreads();
    return buf[0] + buf[1] + buf[2] + buf[3];
}

// ---------------- prep: build bf16 GEMM operands + c_b ----------------
// blocks [0,2048): tail rows -> Tbig[n] = [T^2 (256) | T (256)]
// blocks [2048,2560): head rows -> Abig[b] = [rt^2 | -2*rt*Hh], cvec[b]
__global__ __launch_bounds__(256) void prep_kernel(
        const float* __restrict__ head, const float* __restrict__ tail,
        const float* __restrict__ rel,  const int* __restrict__ rid,
        ushort* __restrict__ Tbig, ushort* __restrict__ Abig,
        float* __restrict__ cvec) {
    __shared__ float buf[4];
    const int tid = threadIdx.x;
    const int blk = blockIdx.x;
    if (blk < N_DIM) {
        const float tv = tail[(size_t)blk * E_DIM + tid];
        const float tot = block_reduce_sum_256(tv * tv, buf);
        const float inv = 1.0f / fmaxf(sqrtf(tot), 1e-12f);
        const float T = tv * inv;
        Tbig[(size_t)blk * K_DIM + tid]          = f2bf(T * T);
        Tbig[(size_t)blk * K_DIM + E_DIM + tid]  = f2bf(T);
    } else {
        const int b = blk - N_DIM;
        const float hv = head[(size_t)b * E_DIM + tid];
        const int id = rid[b];
        const float rh = rel[(size_t)id * (2 * E_DIM) + tid];
        const float rt = rel[(size_t)id * (2 * E_DIM) + E_DIM + tid];
        const float tot = block_reduce_sum_256(hv * hv, buf);
        const float inv = 1.0f / fmaxf(sqrtf(tot), 1e-12f);
        const float Hh = hv * inv * rh;
        Abig[(size_t)b * K_DIM + tid]            = f2bf(rt * rt);
        Abig[(size_t)b * K_DIM + E_DIM + tid]    = f2bf(-2.0f * rt * Hh);
        const float c = block_reduce_sum_256(Hh * Hh, buf);
        if (tid == 0) cvec[b] = c;
    }
}

// ---------------- main GEMM: 64(b) x 64(n) tile per block, K=512 ----------------
// 256 threads = 4 waves; wave w owns b-rows [w*16, w*16+16) x 64 n-cols.
// mfma_f32_16x16x32_bf16: A-frag A[m=lane&15][k=(lane>>4)*8+j],
//                          B-frag B[n=lane&15][k=(lane>>4)*8+j],
//                          D: col=lane&15, row=(lane>>4)*4+reg.
#define KC 128          // K-chunk staged in LDS
#define LDP 136         // padded LDS row stride (ushorts): 272B -> 2-way bank alias (free)

__global__ __launch_bounds__(256) void score_kernel(
        const ushort* __restrict__ Tbig, const ushort* __restrict__ Abig,
        const float* __restrict__ cvec, float* __restrict__ out) {
    __shared__ ushort Ts[64 * LDP];
    __shared__ ushort As[64 * LDP];
    const int tid = threadIdx.x;
    const int n0 = blockIdx.x * 64;
    const int b0 = blockIdx.y * 64;
    const int lane = tid & 63, wv = tid >> 6;
    const int ml = lane & 15, q = lane >> 4;

    f32x4 acc[4];
#pragma unroll
    for (int i = 0; i < 4; ++i) acc[i] = f32x4{0.f, 0.f, 0.f, 0.f};

#pragma unroll
    for (int chunk = 0; chunk < K_DIM / KC; ++chunk) {
        const int k0 = chunk * KC;
        __syncthreads();
        // stage 64 x KC of each operand; 16B per thread-iter, coalesced
        for (int i = tid; i < 64 * (KC / 8); i += 256) {
            const int row = i >> 4;
            const int c = (i & 15) * 8;   // ushort offset within chunk row
            *(uint4*)&Ts[row * LDP + c] =
                *(const uint4*)(Tbig + (size_t)(n0 + row) * K_DIM + k0 + c);
            *(uint4*)&As[row * LDP + c] =
                *(const uint4*)(Abig + (size_t)(b0 + row) * K_DIM + k0 + c);
        }
        __syncthreads();
#pragma unroll
        for (int ks = 0; ks < KC / 32; ++ks) {
            const int k = ks * 32;
            const bf16x8 a = *reinterpret_cast<const bf16x8*>(
                &As[(wv * 16 + ml) * LDP + k + q * 8]);
#pragma unroll
            for (int nt = 0; nt < 4; ++nt) {
                const bf16x8 bb = *reinterpret_cast<const bf16x8*>(
                    &Ts[(nt * 16 + ml) * LDP + k + q * 8]);
                acc[nt] = __builtin_amdgcn_mfma_f32_16x16x32_bf16(a, bb, acc[nt], 0, 0, 0);
            }
        }
    }

    // epilogue: x = acc + c_b ; out = -sqrt(x)
    float cb[4];
#pragma unroll
    for (int r = 0; r < 4; ++r) cb[r] = cvec[b0 + wv * 16 + q * 4 + r];
#pragma unroll
    for (int nt = 0; nt < 4; ++nt) {
        const int n_idx = n0 + nt * 16 + ml;
#pragma unroll
        for (int r = 0; r < 4; ++r) {
            const int b_idx = b0 + wv * 16 + q * 4 + r;
            const float x = acc[nt][r] + cb[r];
            out[(size_t)b_idx * N_DIM + n_idx] = -sqrtf(fmaxf(x, 0.f));
        }
    }
}

// ---------------- fallback (no workspace): pure fp32, correct but slow ----------------
__global__ __launch_bounds__(256) void fallback_kernel(
        const float* __restrict__ head, const float* __restrict__ tail,
        const float* __restrict__ rel,  const int* __restrict__ rid,
        float* __restrict__ out) {
    __shared__ float Hh[E_DIM];
    __shared__ float RT[E_DIM];
    __shared__ float buf[4];
    const int b = blockIdx.x;
    const int tid = threadIdx.x;
    const float hv = head[(size_t)b * E_DIM + tid];
    const int id = rid[b];
    const float rh = rel[(size_t)id * (2 * E_DIM) + tid];
    const float rt = rel[(size_t)id * (2 * E_DIM) + E_DIM + tid];
    const float tot = block_reduce_sum_256(hv * hv, buf);
    const float inv = 1.0f / fmaxf(sqrtf(tot), 1e-12f);
    const float HhV = hv * inv * rh;
    Hh[tid] = HhV; RT[tid] = rt;
    const float c = block_reduce_sum_256(HhV * HhV, buf);
    __syncthreads();
    for (int n = tid; n < N_DIM; n += 256) {
        float S1 = 0.f, S2 = 0.f, Stt = 0.f;
        for (int e = 0; e < E_DIM; ++e) {
            const float tv = tail[(size_t)n * E_DIM + e];
            const float p = tv * RT[e];
            S1 += p * p; S2 += p * Hh[e]; Stt += tv * tv;
        }
        const float al = 1.0f / fmaxf(sqrtf(Stt), 1e-12f);
        const float x = al * al * S1 - 2.0f * al * S2 + c;
        out[(size_t)b * N_DIM + n] = -sqrtf(fmaxf(x, 0.f));
    }
}

extern "C" void kernel_launch(void* const* d_in, const int* in_sizes, int n_in,
                              void* d_out, int out_size, void* d_ws, size_t ws_size,
                              hipStream_t stream) {
    const float* head = (const float*)d_in[0];
    const float* tail = (const float*)d_in[1];
    const float* rel  = (const float*)d_in[2];
    const int*   rid  = (const int*)d_in[3];
    float* out = (float*)d_out;

    const size_t needT = (size_t)N_DIM * K_DIM * sizeof(ushort);   // 2 MB
    const size_t needA = (size_t)B_DIM * K_DIM * sizeof(ushort);   // 512 KB
    const size_t needC = (size_t)B_DIM * sizeof(float);            // 2 KB
    if (ws_size >= needT + needA + needC) {
        ushort* Tbig = (ushort*)d_ws;
        ushort* Abig = Tbig + (size_t)N_DIM * K_DIM;
        float*  cvec = (float*)(Abig + (size_t)B_DIM * K_DIM);
        prep_kernel<<<N_DIM + B_DIM, 256, 0, stream>>>(head, tail, rel, rid,
                                                       Tbig, Abig, cvec);
        dim3 grid(N_DIM / 64, B_DIM / 64);   // 32 x 8 = 256 blocks
        score_kernel<<<grid, 256, 0, stream>>>(Tbig, Abig, cvec, out);
    } else {
        fallback_kernel<<<B_DIM, 256, 0, stream>>>(head, tail, rel, rid, out);
    }
}